// Round 2
// baseline (636.072 us; speedup 1.0000x reference)
//
#include <hip/hip_runtime.h>
#include <hip/hip_bf16.h>

// Problem constants (fixed by setup_inputs)
#define T_TOK 4096   // B*S = 4*1024
#define HD    1024   // hidden
#define FD    2048   // ffn
#define NEXP  8
#define NSH   2

using u16 = unsigned short;
typedef __bf16 bf16x8 __attribute__((ext_vector_type(8)));
typedef float  f32x4  __attribute__((ext_vector_type(4)));

__device__ __forceinline__ u16 f2bf(float f) {
    __hip_bfloat16 h = __float2bfloat16(f);   // RNE
    u16 u; __builtin_memcpy(&u, &h, 2);
    return u;
}

// async global->LDS, 16B per lane. HW: wave-uniform base + lane*16B.
// Per-lane lds ptr below is exactly base + lane*8 u16 == base + lane*16B.
__device__ __forceinline__ void gl2lds16(const u16* g, u16* l) {
    __builtin_amdgcn_global_load_lds((__attribute__((address_space(1))) void*)(g),
                                     (__attribute__((address_space(3))) void*)(l),
                                     16, 0, 0);
}

// ---------------------------------------------------------------------------
// Core 128x128 tile K-loop (BK=32), 4 waves in 2x2, 4x4 16x16x32 MFMA frags.
// a0/a1/b0/b1: per-lane global src ptrs (row*ld + chunk*8 baked in), advance 32/iter.
// ---------------------------------------------------------------------------
__device__ __forceinline__ void gemm_k_loop(
    const u16* a0, const u16* a1, const u16* b0, const u16* b1,
    u16* As, u16* Bs, int kIters, f32x4 acc[4][4])
{
    const int tid  = threadIdx.x;
    const int wave = tid >> 6, lane = tid & 63;
    const int wm = wave >> 1, wn = wave & 1;
    const int l16 = lane & 15, quad = lane >> 4;
    u16* lA0 = As + (wave * 32 + 0)  * 32 + lane * 8;
    u16* lA1 = As + (wave * 32 + 16) * 32 + lane * 8;
    u16* lB0 = Bs + (wave * 32 + 0)  * 32 + lane * 8;
    u16* lB1 = Bs + (wave * 32 + 16) * 32 + lane * 8;

    for (int kt = 0; kt < kIters; ++kt) {
        gl2lds16(a0, lA0);
        gl2lds16(a1, lA1);
        gl2lds16(b0, lB0);
        gl2lds16(b1, lB1);
        a0 += 32; a1 += 32; b0 += 32; b1 += 32;
        __syncthreads();
        bf16x8 af[4], bfv[4];
#pragma unroll
        for (int i = 0; i < 4; ++i)
            af[i] = *(const bf16x8*)(As + (wm * 64 + i * 16 + l16) * 32 + quad * 8);
#pragma unroll
        for (int j = 0; j < 4; ++j)
            bfv[j] = *(const bf16x8*)(Bs + (wn * 64 + j * 16 + l16) * 32 + quad * 8);
#pragma unroll
        for (int i = 0; i < 4; ++i)
#pragma unroll
            for (int j = 0; j < 4; ++j)
                acc[i][j] = __builtin_amdgcn_mfma_f32_16x16x32_bf16(af[i], bfv[j], acc[i][j], 0, 0, 0);
        __syncthreads();
    }
}

__device__ __forceinline__ float gelu_exact(float v) {
    return 0.5f * v * (1.0f + erff(v * 0.70710678118654752440f));
}

// ---------------------------------------------------------------------------
// x fp32 -> bf16
// ---------------------------------------------------------------------------
__global__ __launch_bounds__(256) void convert_x_kernel(
    const float* __restrict__ x, u16* __restrict__ xb)
{
    size_t i = (size_t)(blockIdx.x * 256 + threadIdx.x) * 4;
    float4 v = *(const float4*)(x + i);
    ushort4 o;
    o.x = f2bf(v.x); o.y = f2bf(v.y); o.z = f2bf(v.z); o.w = f2bf(v.w);
    *(ushort4*)(xb + i) = o;
}

// ---------------------------------------------------------------------------
// Router: fp32 logits = x @ router_w + b, top-2 argmax (ties -> lowest index,
// matching jax.lax.top_k on softmaxed scores), append token to expert lists.
// ---------------------------------------------------------------------------
__global__ __launch_bounds__(256) void router_kernel(
    const float* __restrict__ x, const float* __restrict__ rw, const float* __restrict__ rb,
    int* __restrict__ cnt, int* __restrict__ lists)
{
    const int t = blockIdx.x * 4 + (threadIdx.x >> 6);
    const int lane = threadIdx.x & 63;
    float acc[NEXP];
#pragma unroll
    for (int e = 0; e < NEXP; ++e) acc[e] = 0.f;
    for (int it = 0; it < HD / 64; ++it) {
        int h = it * 64 + lane;
        float xv = x[(size_t)t * HD + h];
        const float4* wp = (const float4*)(rw + (size_t)h * NEXP);
        float4 w0 = wp[0], w1 = wp[1];
        acc[0] += xv * w0.x; acc[1] += xv * w0.y; acc[2] += xv * w0.z; acc[3] += xv * w0.w;
        acc[4] += xv * w1.x; acc[5] += xv * w1.y; acc[6] += xv * w1.z; acc[7] += xv * w1.w;
    }
#pragma unroll
    for (int e = 0; e < NEXP; ++e)
        for (int off = 32; off; off >>= 1) acc[e] += __shfl_xor(acc[e], off, 64);
    if (lane == 0) {
#pragma unroll
        for (int e = 0; e < NEXP; ++e) acc[e] += rb[e];
        int b1i = 0;
        for (int e = 1; e < NEXP; ++e) if (acc[e] > acc[b1i]) b1i = e;
        int b2i = (b1i == 0) ? 1 : 0;
        for (int e = 0; e < NEXP; ++e) if (e != b1i && acc[e] > acc[b2i]) b2i = e;
        int p1 = atomicAdd(&cnt[b1i], 1); lists[b1i * T_TOK + p1] = t;
        int p2 = atomicAdd(&cnt[b2i], 1); lists[b2i * T_TOK + p2] = t;
    }
}

__global__ void offsets_kernel(const int* __restrict__ cnt, int* __restrict__ pfx) {
    if (threadIdx.x == 0 && blockIdx.x == 0) {
        int s = 0;
        for (int e = 0; e < NEXP; ++e) { pfx[e] = s; s += ((cnt[e] + 127) >> 7) << 7; }
        pfx[NEXP] = s;
    }
}

// ---------------------------------------------------------------------------
// Weight transposes (fp32 [K,N] -> bf16 [N,K]) into ws; 32x32 LDS tiles.
// ---------------------------------------------------------------------------
__global__ __launch_bounds__(256) void transpose_w1_kernel(
    const float* __restrict__ sw1, const float* __restrict__ ew1, u16* __restrict__ wt)
{
    __shared__ u16 tile[32][33];
    const int z = blockIdx.z;
    const float* src; u16* dst;
    if (z < NSH) { src = sw1 + (size_t)z * HD * FD; dst = wt + (size_t)z * FD * HD; }
    else { src = ew1 + (size_t)(z - NSH) * HD * FD; dst = wt + (size_t)NSH * FD * HD + (size_t)(z - NSH) * FD * HD; }
    const int tx = threadIdx.x, ty = threadIdx.y;
    const int c0 = blockIdx.x * 32, r0 = blockIdx.y * 32;  // r over HD, c over FD
#pragma unroll
    for (int k = 0; k < 4; ++k)
        tile[ty + k * 8][tx] = f2bf(src[(size_t)(r0 + ty + k * 8) * FD + c0 + tx]);
    __syncthreads();
#pragma unroll
    for (int k = 0; k < 4; ++k)
        dst[(size_t)(c0 + ty + k * 8) * HD + r0 + tx] = tile[tx][ty + k * 8];
}

// shared_w2[s][f][h] -> w2tS[h][s*FD+f] (ldd=2*FD);  exp_w2[e][f][h] -> [e][h][f]
__global__ __launch_bounds__(256) void transpose_w2_kernel(
    const float* __restrict__ sw2, const float* __restrict__ ew2, u16* __restrict__ wt)
{
    __shared__ u16 tile[32][33];
    const int z = blockIdx.z;
    const float* src; u16* dst; int ldd;
    if (z < NSH) { src = sw2 + (size_t)z * FD * HD; dst = wt + (size_t)z * FD; ldd = 2 * FD; }
    else { src = ew2 + (size_t)(z - NSH) * FD * HD; dst = wt + (size_t)NSH * FD * HD + (size_t)(z - NSH) * HD * FD; ldd = FD; }
    const int tx = threadIdx.x, ty = threadIdx.y;
    const int c0 = blockIdx.x * 32, r0 = blockIdx.y * 32;  // r over FD, c over HD
#pragma unroll
    for (int k = 0; k < 4; ++k)
        tile[ty + k * 8][tx] = f2bf(src[(size_t)(r0 + ty + k * 8) * HD + c0 + tx]);
    __syncthreads();
#pragma unroll
    for (int k = 0; k < 4; ++k)
        dst[(size_t)(c0 + ty + k * 8) * ldd + r0 + tx] = tile[tx][ty + k * 8];
}

// ---------------------------------------------------------------------------
// GEMM1 shared: hidS[t][s*FD+f] = gelu(x @ w1_s + b1_s)
// ---------------------------------------------------------------------------
__global__ __launch_bounds__(256, 2) void gemm1_shared_kernel(
    const u16* __restrict__ xb, const u16* __restrict__ w1t,
    const float* __restrict__ bias1, u16* __restrict__ hidS)
{
    __shared__ __align__(16) u16 As[128 * 32];
    __shared__ __align__(16) u16 Bs[128 * 32];
    const int nt = blockIdx.x, mt = blockIdx.y, s = blockIdx.z;
    const int tid = threadIdx.x, wave = tid >> 6, lane = tid & 63;
    const int r0 = wave * 32 + (lane >> 2), ch = (lane & 3) * 8;
    const u16* a0 = xb + (size_t)(mt * 128 + r0) * HD + ch;
    const u16* a1 = a0 + (size_t)16 * HD;
    const u16* b0 = w1t + (size_t)s * FD * HD + (size_t)(nt * 128 + r0) * HD + ch;
    const u16* b1 = b0 + (size_t)16 * HD;
    f32x4 acc[4][4] = {};
    gemm_k_loop(a0, a1, b0, b1, As, Bs, HD / 32, acc);
    const int wm = wave >> 1, wn = wave & 1, l16 = lane & 15, quad = lane >> 4;
#pragma unroll
    for (int j = 0; j < 4; ++j) {
        int f = nt * 128 + wn * 64 + j * 16 + l16;
        float bv = bias1[s * FD + f];
#pragma unroll
        for (int i = 0; i < 4; ++i) {
            int row = mt * 128 + wm * 64 + i * 16 + quad * 4;
#pragma unroll
            for (int r = 0; r < 4; ++r)
                hidS[(size_t)(row + r) * (2 * FD) + s * FD + f] = f2bf(gelu_exact(acc[i][j][r] + bv));
        }
    }
}

// ---------------------------------------------------------------------------
// GEMM1 routed: rows gathered via per-expert token list.
// ---------------------------------------------------------------------------
__global__ __launch_bounds__(256, 2) void gemm1_routed_kernel(
    const u16* __restrict__ xb, const u16* __restrict__ w1te,
    const float* __restrict__ eb1, const int* __restrict__ cnt,
    const int* __restrict__ pfx, const int* __restrict__ lists,
    u16* __restrict__ hidE)
{
    const int e = blockIdx.z, mt = blockIdx.y, nt = blockIdx.x;
    const int n_e = cnt[e];
    if (mt * 128 >= n_e) return;  // block-uniform early-exit
    __shared__ __align__(16) u16 As[128 * 32];
    __shared__ __align__(16) u16 Bs[128 * 32];
    const int tid = threadIdx.x, wave = tid >> 6, lane = tid & 63;
    const int r0 = wave * 32 + (lane >> 2), ch = (lane & 3) * 8;
    const int tok0 = lists[e * T_TOK + mt * 128 + r0];        // padded slots are 0 (memset)
    const int tok1 = lists[e * T_TOK + mt * 128 + r0 + 16];
    const u16* a0 = xb + (size_t)tok0 * HD + ch;
    const u16* a1 = xb + (size_t)tok1 * HD + ch;
    const u16* b0 = w1te + (size_t)e * FD * HD + (size_t)(nt * 128 + r0) * HD + ch;
    const u16* b1 = b0 + (size_t)16 * HD;
    f32x4 acc[4][4] = {};
    gemm_k_loop(a0, a1, b0, b1, As, Bs, HD / 32, acc);
    const int base = pfx[e];
    const int wm = wave >> 1, wn = wave & 1, l16 = lane & 15, quad = lane >> 4;
#pragma unroll
    for (int j = 0; j < 4; ++j) {
        int f = nt * 128 + wn * 64 + j * 16 + l16;
        float bv = eb1[e * FD + f];
#pragma unroll
        for (int i = 0; i < 4; ++i) {
            int row = base + mt * 128 + wm * 64 + i * 16 + quad * 4;
#pragma unroll
            for (int r = 0; r < 4; ++r)
                hidE[(size_t)(row + r) * FD + f] = f2bf(gelu_exact(acc[i][j][r] + bv));
        }
    }
}

// ---------------------------------------------------------------------------
// GEMM2 shared: out[t][h] += hidS[t][:] . w2tS[h][:]  (K=4096 covers both
// shared experts; K-split over blockIdx.z, atomicAdd into zeroed fp32 out)
// ---------------------------------------------------------------------------
__global__ __launch_bounds__(256, 2) void gemm2_shared_kernel(
    const u16* __restrict__ hidS, const u16* __restrict__ w2tS,
    const float* __restrict__ sb2, float* __restrict__ out)
{
    __shared__ __align__(16) u16 As[128 * 32];
    __shared__ __align__(16) u16 Bs[128 * 32];
    const int nt = blockIdx.x, mt = blockIdx.y, kh = blockIdx.z;
    const int tid = threadIdx.x, wave = tid >> 6, lane = tid & 63;
    const int r0 = wave * 32 + (lane >> 2), ch = (lane & 3) * 8;
    const u16* a0 = hidS + (size_t)(mt * 128 + r0) * (2 * FD) + kh * FD + ch;
    const u16* a1 = a0 + (size_t)16 * (2 * FD);
    const u16* b0 = w2tS + (size_t)(nt * 128 + r0) * (2 * FD) + kh * FD + ch;
    const u16* b1 = b0 + (size_t)16 * (2 * FD);
    f32x4 acc[4][4] = {};
    gemm_k_loop(a0, a1, b0, b1, As, Bs, FD / 32, acc);
    const int wm = wave >> 1, wn = wave & 1, l16 = lane & 15, quad = lane >> 4;
#pragma unroll
    for (int j = 0; j < 4; ++j) {
        int h = nt * 128 + wn * 64 + j * 16 + l16;
        float bv = (kh == 0) ? (sb2[h] + sb2[HD + h]) : 0.f;
#pragma unroll
        for (int i = 0; i < 4; ++i) {
            int row = mt * 128 + wm * 64 + i * 16 + quad * 4;
#pragma unroll
            for (int r = 0; r < 4; ++r)
                atomicAdd(&out[(size_t)(row + r) * HD + h], acc[i][j][r] + bv);
        }
    }
}

// ---------------------------------------------------------------------------
// GEMM2 routed: scatter per-token via list, atomicAdd; K-split on z parity.
// ---------------------------------------------------------------------------
__global__ __launch_bounds__(256, 2) void gemm2_routed_kernel(
    const u16* __restrict__ hidE, const u16* __restrict__ w2te,
    const float* __restrict__ eb2, const int* __restrict__ cnt,
    const int* __restrict__ pfx, const int* __restrict__ lists,
    float* __restrict__ out)
{
    const int z = blockIdx.z, e = z >> 1, kh = z & 1;
    const int mt = blockIdx.y, nt = blockIdx.x;
    const int n_e = cnt[e];
    if (mt * 128 >= n_e) return;
    __shared__ __align__(16) u16 As[128 * 32];
    __shared__ __align__(16) u16 Bs[128 * 32];
    const int tid = threadIdx.x, wave = tid >> 6, lane = tid & 63;
    const int r0 = wave * 32 + (lane >> 2), ch = (lane & 3) * 8;
    const int base = pfx[e];
    const u16* a0 = hidE + (size_t)(base + mt * 128 + r0) * FD + kh * HD + ch;
    const u16* a1 = a0 + (size_t)16 * FD;
    const u16* b0 = w2te + (size_t)e * HD * FD + (size_t)(nt * 128 + r0) * FD + kh * HD + ch;
    const u16* b1 = b0 + (size_t)16 * FD;
    f32x4 acc[4][4] = {};
    gemm_k_loop(a0, a1, b0, b1, As, Bs, HD / 32, acc);
    const int wm = wave >> 1, wn = wave & 1, l16 = lane & 15, quad = lane >> 4;
#pragma unroll
    for (int j = 0; j < 4; ++j) {
        int h = nt * 128 + wn * 64 + j * 16 + l16;
        float bv = (kh == 0) ? eb2[e * HD + h] : 0.f;
#pragma unroll
        for (int i = 0; i < 4; ++i) {
            int local = mt * 128 + wm * 64 + i * 16 + quad * 4;
#pragma unroll
            for (int r = 0; r < 4; ++r) {
                if (local + r < n_e) {
                    int t = lists[e * T_TOK + local + r];
                    atomicAdd(&out[(size_t)t * HD + h], acc[i][j][r] + bv);
                }
            }
        }
    }
}

// ---------------------------------------------------------------------------
// Workspace layout (bytes):
//   xb     @ 0           :  8,388,608  (bf16 x [4096][1024])
//   wt     @ 8,388,608   : 41,943,040  (bf16 w1^T, later reused for w2^T)
//   hidS   @ 50,331,648  : 33,554,432  (bf16 [4096][2*FD])
//   hidE   @ 83,886,080  : 37,748,736  (bf16 [9216][FD], 128-padded per expert)
//   cnt    @ 121,634,816 : 64
//   pfx    @ 121,634,880 : 64
//   lists  @ 121,634,944 : 131,072
// total ~116.2 MB
// ---------------------------------------------------------------------------
extern "C" void kernel_launch(void* const* d_in, const int* in_sizes, int n_in,
                              void* d_out, int out_size, void* d_ws, size_t ws_size,
                              hipStream_t stream)
{
    const float* x   = (const float*)d_in[0];
    const float* sw1 = (const float*)d_in[1];
    const float* sb1 = (const float*)d_in[2];
    const float* sw2 = (const float*)d_in[3];
    const float* sb2 = (const float*)d_in[4];
    const float* ew1 = (const float*)d_in[5];
    const float* eb1 = (const float*)d_in[6];
    const float* ew2 = (const float*)d_in[7];
    const float* eb2 = (const float*)d_in[8];
    const float* rw  = (const float*)d_in[9];
    const float* rb  = (const float*)d_in[10];
    float* out = (float*)d_out;

    char* ws   = (char*)d_ws;
    u16*  xb   = (u16*)ws;
    u16*  wt   = xb + (size_t)4194304;
    u16*  hidS = wt + (size_t)20971520;
    u16*  hidE = hidS + (size_t)16777216;
    int*  cnt  = (int*)(ws + 121634816);
    int*  pfx  = (int*)(ws + 121634880);
    int*  lists = (int*)(ws + 121634944);

    hipMemsetAsync(out, 0, (size_t)T_TOK * HD * sizeof(float), stream);
    hipMemsetAsync(cnt, 0, 128 + (size_t)NEXP * T_TOK * 4, stream);  // cnt+pfx+lists

    convert_x_kernel<<<dim3(T_TOK * HD / 4 / 256), dim3(256), 0, stream>>>(x, xb);
    router_kernel<<<dim3(T_TOK / 4), dim3(256), 0, stream>>>(x, rw, rb, cnt, lists);
    offsets_kernel<<<dim3(1), dim3(64), 0, stream>>>(cnt, pfx);
    transpose_w1_kernel<<<dim3(FD / 32, HD / 32, NSH + NEXP), dim3(32, 8), 0, stream>>>(sw1, ew1, wt);

    gemm1_shared_kernel<<<dim3(FD / 128, T_TOK / 128, NSH), dim3(256), 0, stream>>>(xb, wt, sb1, hidS);
    gemm1_routed_kernel<<<dim3(FD / 128, T_TOK / 128, NEXP), dim3(256), 0, stream>>>(
        xb, wt + (size_t)NSH * FD * HD, eb1, cnt, pfx, lists, hidE);

    transpose_w2_kernel<<<dim3(HD / 32, FD / 32, NSH + NEXP), dim3(32, 8), 0, stream>>>(sw2, ew2, wt);

    gemm2_shared_kernel<<<dim3(HD / 128, T_TOK / 128, 2), dim3(256), 0, stream>>>(hidS, wt, sb2, out);
    gemm2_routed_kernel<<<dim3(HD / 128, T_TOK / 128, NEXP * 2), dim3(256), 0, stream>>>(
        hidE, wt + (size_t)NSH * FD * HD, eb2, cnt, pfx, lists, out);
}

// Round 3
// 556.545 us; speedup vs baseline: 1.1429x; 1.1429x over previous
//
#include <hip/hip_runtime.h>
#include <hip/hip_bf16.h>

// Problem constants (fixed by setup_inputs)
#define T_TOK 4096   // B*S = 4*1024
#define HD    1024   // hidden
#define FD    2048   // ffn
#define NEXP  8
#define NSH   2

using u16 = unsigned short;
typedef __bf16 bf16x8 __attribute__((ext_vector_type(8)));
typedef float  f32x4  __attribute__((ext_vector_type(4)));
typedef u16    u16x2  __attribute__((ext_vector_type(2)));

__device__ __forceinline__ u16 f2bf(float f) {
    __hip_bfloat16 h = __float2bfloat16(f);   // RNE
    u16 u; __builtin_memcpy(&u, &h, 2);
    return u;
}
__device__ __forceinline__ float bf2f(u16 u) {
    unsigned v = ((unsigned)u) << 16;
    float f; __builtin_memcpy(&f, &v, 4);
    return f;
}

// async global->LDS, 16B per lane. HW: wave-uniform base + lane*16B.
__device__ __forceinline__ void gl2lds16(const u16* g, u16* l) {
    __builtin_amdgcn_global_load_lds((__attribute__((address_space(1))) void*)(g),
                                     (__attribute__((address_space(3))) void*)(l),
                                     16, 0, 0);
}

// ---------------------------------------------------------------------------
// Core 128x128 tile K-loop (BK=32), 4 waves in 2x2, 4x4 16x16x32 MFMA frags.
// ---------------------------------------------------------------------------
__device__ __forceinline__ void gemm_k_loop(
    const u16* a0, const u16* a1, const u16* b0, const u16* b1,
    u16* As, u16* Bs, int kIters, f32x4 acc[4][4])
{
    const int tid  = threadIdx.x;
    const int wave = tid >> 6, lane = tid & 63;
    const int wm = wave >> 1, wn = wave & 1;
    const int l16 = lane & 15, quad = lane >> 4;
    u16* lA0 = As + (wave * 32 + 0)  * 32 + lane * 8;
    u16* lA1 = As + (wave * 32 + 16) * 32 + lane * 8;
    u16* lB0 = Bs + (wave * 32 + 0)  * 32 + lane * 8;
    u16* lB1 = Bs + (wave * 32 + 16) * 32 + lane * 8;

    for (int kt = 0; kt < kIters; ++kt) {
        gl2lds16(a0, lA0);
        gl2lds16(a1, lA1);
        gl2lds16(b0, lB0);
        gl2lds16(b1, lB1);
        a0 += 32; a1 += 32; b0 += 32; b1 += 32;
        __syncthreads();
        bf16x8 af[4], bfv[4];
#pragma unroll
        for (int i = 0; i < 4; ++i)
            af[i] = *(const bf16x8*)(As + (wm * 64 + i * 16 + l16) * 32 + quad * 8);
#pragma unroll
        for (int j = 0; j < 4; ++j)
            bfv[j] = *(const bf16x8*)(Bs + (wn * 64 + j * 16 + l16) * 32 + quad * 8);
#pragma unroll
        for (int i = 0; i < 4; ++i)
#pragma unroll
            for (int j = 0; j < 4; ++j)
                acc[i][j] = __builtin_amdgcn_mfma_f32_16x16x32_bf16(af[i], bfv[j], acc[i][j], 0, 0, 0);
        __syncthreads();
    }
}

__device__ __forceinline__ float gelu_exact(float v) {
    return 0.5f * v * (1.0f + erff(v * 0.70710678118654752440f));
}

// ---------------------------------------------------------------------------
// x fp32 -> bf16
// ---------------------------------------------------------------------------
__global__ __launch_bounds__(256) void convert_x_kernel(
    const float* __restrict__ x, u16* __restrict__ xb)
{
    size_t i = (size_t)(blockIdx.x * 256 + threadIdx.x) * 4;
    float4 v = *(const float4*)(x + i);
    ushort4 o;
    o.x = f2bf(v.x); o.y = f2bf(v.y); o.z = f2bf(v.z); o.w = f2bf(v.w);
    *(ushort4*)(xb + i) = o;
}

// ---------------------------------------------------------------------------
// Router: fp32 logits, top-2 argmax (ties -> lowest index). Appends token to
// expert list AND records (e,p) in pos[t][k] for the finalize gather.
// ---------------------------------------------------------------------------
__global__ __launch_bounds__(256) void router_kernel(
    const float* __restrict__ x, const float* __restrict__ rw, const float* __restrict__ rb,
    int* __restrict__ cnt, int* __restrict__ lists, int* __restrict__ pos)
{
    const int t = blockIdx.x * 4 + (threadIdx.x >> 6);
    const int lane = threadIdx.x & 63;
    float acc[NEXP];
#pragma unroll
    for (int e = 0; e < NEXP; ++e) acc[e] = 0.f;
    for (int it = 0; it < HD / 64; ++it) {
        int h = it * 64 + lane;
        float xv = x[(size_t)t * HD + h];
        const float4* wp = (const float4*)(rw + (size_t)h * NEXP);
        float4 w0 = wp[0], w1 = wp[1];
        acc[0] += xv * w0.x; acc[1] += xv * w0.y; acc[2] += xv * w0.z; acc[3] += xv * w0.w;
        acc[4] += xv * w1.x; acc[5] += xv * w1.y; acc[6] += xv * w1.z; acc[7] += xv * w1.w;
    }
#pragma unroll
    for (int e = 0; e < NEXP; ++e)
        for (int off = 32; off; off >>= 1) acc[e] += __shfl_xor(acc[e], off, 64);
    if (lane == 0) {
#pragma unroll
        for (int e = 0; e < NEXP; ++e) acc[e] += rb[e];
        int b1i = 0;
        for (int e = 1; e < NEXP; ++e) if (acc[e] > acc[b1i]) b1i = e;
        int b2i = (b1i == 0) ? 1 : 0;
        for (int e = 0; e < NEXP; ++e) if (e != b1i && acc[e] > acc[b2i]) b2i = e;
        int p1 = atomicAdd(&cnt[b1i], 1); lists[b1i * T_TOK + p1] = t;
        int p2 = atomicAdd(&cnt[b2i], 1); lists[b2i * T_TOK + p2] = t;
        pos[2 * t]     = (b1i << 13) | p1;
        pos[2 * t + 1] = (b2i << 13) | p2;
    }
}

__global__ void offsets_kernel(const int* __restrict__ cnt, int* __restrict__ pfx) {
    if (threadIdx.x == 0 && blockIdx.x == 0) {
        int s = 0;
        for (int e = 0; e < NEXP; ++e) { pfx[e] = s; s += ((cnt[e] + 127) >> 7) << 7; }
        pfx[NEXP] = s;
    }
}

// ---------------------------------------------------------------------------
// Transposes: fp32 [K,N] -> bf16 [N,K]. 64(dst-contig dim) x 32 tiles;
// 128B/wave reads AND writes (u16x2). LDS tile[c][r] padded to 65.
// ---------------------------------------------------------------------------
__global__ __launch_bounds__(256) void transpose_w1_kernel(
    const float* __restrict__ sw1, const float* __restrict__ ew1, u16* __restrict__ wt)
{
    __shared__ u16 tile[32][65];
    const int z = blockIdx.z;
    const float* src = (z < NSH) ? (sw1 + (size_t)z * HD * FD)
                                 : (ew1 + (size_t)(z - NSH) * HD * FD);
    u16* dst = wt + (size_t)z * FD * HD;           // [f][h], ld = HD
    const int tx = threadIdx.x, ty = threadIdx.y;  // (32, 8)
    const int c0 = blockIdx.x * 32;                // over FD (dst rows)
    const int r0 = blockIdx.y * 64;                // over HD (dst contig)
#pragma unroll
    for (int k = 0; k < 8; ++k)
        tile[tx][ty + 8 * k] = f2bf(src[(size_t)(r0 + ty + 8 * k) * FD + c0 + tx]);
    __syncthreads();
#pragma unroll
    for (int k = 0; k < 4; ++k) {
        int c = ty + 8 * k;
        u16x2 v = { tile[c][2 * tx], tile[c][2 * tx + 1] };
        *(u16x2*)(dst + (size_t)(c0 + c) * HD + r0 + 2 * tx) = v;
    }
}

// shared_w2[s][f][h] -> w2tS[h][s*FD+f] (ld=2FD);  exp_w2[e][f][h] -> [e][h][f]
__global__ __launch_bounds__(256) void transpose_w2_kernel(
    const float* __restrict__ sw2, const float* __restrict__ ew2, u16* __restrict__ wt)
{
    __shared__ u16 tile[32][65];
    const int z = blockIdx.z;
    const float* src; u16* dst; size_t ldd;
    if (z < NSH) { src = sw2 + (size_t)z * FD * HD; dst = wt + (size_t)z * FD; ldd = 2 * FD; }
    else { src = ew2 + (size_t)(z - NSH) * FD * HD;
           dst = wt + (size_t)NSH * FD * HD + (size_t)(z - NSH) * HD * FD; ldd = FD; }
    const int tx = threadIdx.x, ty = threadIdx.y;  // (32, 8)
    const int c0 = blockIdx.x * 32;                // over HD (dst rows h)
    const int r0 = blockIdx.y * 64;                // over FD (dst contig f)
#pragma unroll
    for (int k = 0; k < 8; ++k)
        tile[tx][ty + 8 * k] = f2bf(src[(size_t)(r0 + ty + 8 * k) * HD + c0 + tx]);
    __syncthreads();
#pragma unroll
    for (int k = 0; k < 4; ++k) {
        int c = ty + 8 * k;
        u16x2 v = { tile[c][2 * tx], tile[c][2 * tx + 1] };
        *(u16x2*)(dst + (size_t)(c0 + c) * ldd + r0 + 2 * tx) = v;
    }
}

// ---------------------------------------------------------------------------
// GEMM1 merged: z<NSH -> shared expert s=z (hidS[t][s*FD+f]);
//               z>=NSH -> routed expert e=z-NSH (hidE[pfx[e]+slot][f]).
// ---------------------------------------------------------------------------
__global__ __launch_bounds__(256, 4) void gemm1_all_kernel(
    const u16* __restrict__ xb, const u16* __restrict__ w1t,
    const float* __restrict__ sb1, const float* __restrict__ eb1,
    const int* __restrict__ cnt, const int* __restrict__ pfx,
    const int* __restrict__ lists,
    u16* __restrict__ hidS, u16* __restrict__ hidE)
{
    const int z = blockIdx.z, nt = blockIdx.x, mt = blockIdx.y;
    const bool routed = (z >= NSH);
    const int e = z - NSH;
    if (routed && mt * 128 >= cnt[e]) return;   // block-uniform early exit
    __shared__ __align__(16) u16 As[128 * 32];
    __shared__ __align__(16) u16 Bs[128 * 32];
    const int tid = threadIdx.x, wave = tid >> 6, lane = tid & 63;
    const int r0 = wave * 32 + (lane >> 2), ch = (lane & 3) * 8;
    const u16 *a0, *a1;
    if (routed) {
        int tok0 = lists[e * T_TOK + mt * 128 + r0];
        int tok1 = lists[e * T_TOK + mt * 128 + r0 + 16];
        a0 = xb + (size_t)tok0 * HD + ch;
        a1 = xb + (size_t)tok1 * HD + ch;
    } else {
        a0 = xb + (size_t)(mt * 128 + r0) * HD + ch;
        a1 = a0 + (size_t)16 * HD;
    }
    const u16* b0 = w1t + (size_t)z * FD * HD + (size_t)(nt * 128 + r0) * HD + ch;
    const u16* b1 = b0 + (size_t)16 * HD;
    f32x4 acc[4][4] = {};
    gemm_k_loop(a0, a1, b0, b1, As, Bs, HD / 32, acc);

    const float* bias = routed ? (eb1 + e * FD) : (sb1 + z * FD);
    u16* dst   = routed ? hidE : hidS;
    const size_t ld = routed ? FD : 2 * FD;
    const int rowbase = routed ? (pfx[e] + mt * 128) : (mt * 128);
    const int colofs  = routed ? 0 : z * FD;
    const int wm = wave >> 1, wn = wave & 1, l16 = lane & 15, quad = lane >> 4;
#pragma unroll
    for (int j = 0; j < 4; ++j) {
        int f = nt * 128 + wn * 64 + j * 16 + l16;
        float bv = bias[f];
#pragma unroll
        for (int i = 0; i < 4; ++i) {
            int row = rowbase + wm * 64 + i * 16 + quad * 4;
#pragma unroll
            for (int r = 0; r < 4; ++r)
                dst[(size_t)(row + r) * ld + colofs + f] = f2bf(gelu_exact(acc[i][j][r] + bv));
        }
    }
}

// ---------------------------------------------------------------------------
// GEMM2 merged, NO atomics: z==0 -> shared (K=4096 over both experts, plain
// stores directly to out w/ both biases); z>=1 -> routed expert e=z-1
// (K=2048, plain stores to routedOut[slot] bf16 w/ bias).
// ---------------------------------------------------------------------------
__global__ __launch_bounds__(256, 4) void gemm2_all_kernel(
    const u16* __restrict__ hidS, const u16* __restrict__ hidE,
    const u16* __restrict__ w2t,
    const float* __restrict__ sb2, const float* __restrict__ eb2,
    const int* __restrict__ cnt, const int* __restrict__ pfx,
    float* __restrict__ out, u16* __restrict__ routedOut)
{
    const int z = blockIdx.z, nt = blockIdx.x, mt = blockIdx.y;
    const int e = z - 1;
    if (z >= 1 && mt * 128 >= cnt[e]) return;
    __shared__ __align__(16) u16 As[128 * 32];
    __shared__ __align__(16) u16 Bs[128 * 32];
    const int tid = threadIdx.x, wave = tid >> 6, lane = tid & 63;
    const int r0 = wave * 32 + (lane >> 2), ch = (lane & 3) * 8;
    const int wm = wave >> 1, wn = wave & 1, l16 = lane & 15, quad = lane >> 4;
    f32x4 acc[4][4] = {};

    if (z == 0) {
        const u16* a0 = hidS + (size_t)(mt * 128 + r0) * (2 * FD) + ch;
        const u16* a1 = a0 + (size_t)16 * (2 * FD);
        const u16* b0 = w2t + (size_t)(nt * 128 + r0) * (2 * FD) + ch;
        const u16* b1 = b0 + (size_t)16 * (2 * FD);
        gemm_k_loop(a0, a1, b0, b1, As, Bs, (2 * FD) / 32, acc);
#pragma unroll
        for (int j = 0; j < 4; ++j) {
            int h = nt * 128 + wn * 64 + j * 16 + l16;
            float bv = sb2[h] + sb2[HD + h];
#pragma unroll
            for (int i = 0; i < 4; ++i) {
                int row = mt * 128 + wm * 64 + i * 16 + quad * 4;
#pragma unroll
                for (int r = 0; r < 4; ++r)
                    out[(size_t)(row + r) * HD + h] = acc[i][j][r] + bv;
            }
        }
    } else {
        const int base = pfx[e];
        const u16* a0 = hidE + (size_t)(base + mt * 128 + r0) * FD + ch;
        const u16* a1 = a0 + (size_t)16 * FD;
        const u16* b0 = w2t + (size_t)NSH * FD * HD + (size_t)e * HD * FD
                            + (size_t)(nt * 128 + r0) * FD + ch;
        const u16* b1 = b0 + (size_t)16 * FD;
        gemm_k_loop(a0, a1, b0, b1, As, Bs, FD / 32, acc);
#pragma unroll
        for (int j = 0; j < 4; ++j) {
            int h = nt * 128 + wn * 64 + j * 16 + l16;
            float bv = eb2[e * HD + h];
#pragma unroll
            for (int i = 0; i < 4; ++i) {
                int row = base + mt * 128 + wm * 64 + i * 16 + quad * 4;
#pragma unroll
                for (int r = 0; r < 4; ++r)
                    routedOut[(size_t)(row + r) * HD + h] = f2bf(acc[i][j][r] + bv);
            }
        }
    }
}

// Fallback (small-ws): routed scatters via atomicAdd onto out (which the
// shared pass already fully wrote). K unsplit, bias added once per (t,h,e).
__global__ __launch_bounds__(256, 4) void gemm2_routed_atomic_kernel(
    const u16* __restrict__ hidE, const u16* __restrict__ w2t,
    const float* __restrict__ eb2, const int* __restrict__ cnt,
    const int* __restrict__ pfx, const int* __restrict__ lists,
    float* __restrict__ out)
{
    const int e = blockIdx.z, nt = blockIdx.x, mt = blockIdx.y;
    const int n_e = cnt[e];
    if (mt * 128 >= n_e) return;
    __shared__ __align__(16) u16 As[128 * 32];
    __shared__ __align__(16) u16 Bs[128 * 32];
    const int tid = threadIdx.x, wave = tid >> 6, lane = tid & 63;
    const int r0 = wave * 32 + (lane >> 2), ch = (lane & 3) * 8;
    const int base = pfx[e];
    const u16* a0 = hidE + (size_t)(base + mt * 128 + r0) * FD + ch;
    const u16* a1 = a0 + (size_t)16 * FD;
    const u16* b0 = w2t + (size_t)NSH * FD * HD + (size_t)e * HD * FD
                        + (size_t)(nt * 128 + r0) * FD + ch;
    const u16* b1 = b0 + (size_t)16 * FD;
    f32x4 acc[4][4] = {};
    gemm_k_loop(a0, a1, b0, b1, As, Bs, FD / 32, acc);
    const int wm = wave >> 1, wn = wave & 1, l16 = lane & 15, quad = lane >> 4;
#pragma unroll
    for (int j = 0; j < 4; ++j) {
        int h = nt * 128 + wn * 64 + j * 16 + l16;
        float bv = eb2[e * HD + h];
#pragma unroll
        for (int i = 0; i < 4; ++i) {
            int local = mt * 128 + wm * 64 + i * 16 + quad * 4;
#pragma unroll
            for (int r = 0; r < 4; ++r)
                if (local + r < n_e) {
                    int t = lists[e * T_TOK + local + r];
                    atomicAdd(&out[(size_t)t * HD + h], acc[i][j][r] + bv);
                }
        }
    }
}

// out[t][:] += routedOut[row1][:] + routedOut[row2][:]
__global__ __launch_bounds__(256) void finalize_kernel(
    const u16* __restrict__ routedOut, const int* __restrict__ pos,
    const int* __restrict__ pfx, float* __restrict__ out)
{
    const int t = blockIdx.x;
    int enc0 = pos[2 * t], enc1 = pos[2 * t + 1];
    int row0 = pfx[enc0 >> 13] + (enc0 & 8191);
    int row1 = pfx[enc1 >> 13] + (enc1 & 8191);
    int h = threadIdx.x * 4;
    ushort4 a = *(const ushort4*)(routedOut + (size_t)row0 * HD + h);
    ushort4 b = *(const ushort4*)(routedOut + (size_t)row1 * HD + h);
    float* po = out + (size_t)t * HD + h;
    float4 o = *(const float4*)po;
    o.x += bf2f(a.x) + bf2f(b.x);
    o.y += bf2f(a.y) + bf2f(b.y);
    o.z += bf2f(a.z) + bf2f(b.z);
    o.w += bf2f(a.w) + bf2f(b.w);
    *(float4*)po = o;
}

// ---------------------------------------------------------------------------
// Workspace layout (bytes):
//   wt        @ 0           : 41,943,040  (w1^T, later reused for w2^T)
//   hidS      @ 41,943,040  : 33,554,432  (bf16 [4096][2*FD])
//   hidE      @ 75,497,472  : 37,748,736  (bf16 [9216][FD])
//   xb        @ 113,246,208 :  8,388,608  (dead after gemm1)
//   routedOut @ 113,246,208 : 18,874,368  (overlays xb; lifetimes disjoint)
// primary: smalls @ 132,120,576 (cnt 64 | pfx 64 | lists 131072 | pos 32768)
//          -> total 132,284,544
// fallback: smalls @ 121,634,816 -> total 121,798,784 (proven-safe size)
// ---------------------------------------------------------------------------
extern "C" void kernel_launch(void* const* d_in, const int* in_sizes, int n_in,
                              void* d_out, int out_size, void* d_ws, size_t ws_size,
                              hipStream_t stream)
{
    (void)in_sizes; (void)n_in; (void)out_size;
    const float* x   = (const float*)d_in[0];
    const float* sw1 = (const float*)d_in[1];
    const float* sb1 = (const float*)d_in[2];
    const float* sw2 = (const float*)d_in[3];
    const float* sb2 = (const float*)d_in[4];
    const float* ew1 = (const float*)d_in[5];
    const float* eb1 = (const float*)d_in[6];
    const float* ew2 = (const float*)d_in[7];
    const float* eb2 = (const float*)d_in[8];
    const float* rw  = (const float*)d_in[9];
    const float* rb  = (const float*)d_in[10];
    float* out = (float*)d_out;

    const bool plain = (ws_size >= (size_t)132284544);
    char* ws   = (char*)d_ws;
    u16*  wt   = (u16*)ws;
    u16*  hidS = (u16*)(ws + 41943040);
    u16*  hidE = (u16*)(ws + 75497472);
    u16*  xb   = (u16*)(ws + 113246208);
    u16*  rOut = (u16*)(ws + 113246208);   // overlays xb
    size_t smallOfs = plain ? (size_t)132120576 : (size_t)121634816;
    int*  cnt   = (int*)(ws + smallOfs);
    int*  pfx   = (int*)(ws + smallOfs + 64);
    int*  lists = (int*)(ws + smallOfs + 128);
    int*  pos   = (int*)(ws + smallOfs + 128 + NEXP * T_TOK * 4);

    hipMemsetAsync(cnt, 0, 128 + (size_t)NEXP * T_TOK * 4, stream);  // cnt+pfx+lists

    convert_x_kernel<<<dim3(T_TOK * HD / 4 / 256), dim3(256), 0, stream>>>(x, xb);
    router_kernel<<<dim3(T_TOK / 4), dim3(256), 0, stream>>>(x, rw, rb, cnt, lists, pos);
    offsets_kernel<<<dim3(1), dim3(64), 0, stream>>>(cnt, pfx);
    transpose_w1_kernel<<<dim3(FD / 32, HD / 64, NSH + NEXP), dim3(32, 8), 0, stream>>>(sw1, ew1, wt);

    gemm1_all_kernel<<<dim3(FD / 128, T_TOK / 128, NSH + NEXP), dim3(256), 0, stream>>>(
        xb, wt, sb1, eb1, cnt, pfx, lists, hidS, hidE);

    transpose_w2_kernel<<<dim3(HD / 32, FD / 64, NSH + NEXP), dim3(32, 8), 0, stream>>>(sw2, ew2, wt);

    if (plain) {
        gemm2_all_kernel<<<dim3(HD / 128, T_TOK / 128, 1 + NEXP), dim3(256), 0, stream>>>(
            hidS, hidE, wt, sb2, eb2, cnt, pfx, out, rOut);
        finalize_kernel<<<dim3(T_TOK), dim3(256), 0, stream>>>(rOut, pos, pfx, out);
    } else {
        gemm2_all_kernel<<<dim3(HD / 128, T_TOK / 128, 1), dim3(256), 0, stream>>>(
            hidS, hidE, wt, sb2, eb2, cnt, pfx, out, rOut);  // z=0 shared only
        gemm2_routed_atomic_kernel<<<dim3(HD / 128, T_TOK / 128, NEXP), dim3(256), 0, stream>>>(
            hidE, wt, eb2, cnt, pfx, lists, out);
    }
}

// Round 4
// 528.977 us; speedup vs baseline: 1.2025x; 1.0521x over previous
//
#include <hip/hip_runtime.h>
#include <hip/hip_bf16.h>

// Problem constants (fixed by setup_inputs)
#define T_TOK 4096   // B*S = 4*1024
#define HD    1024   // hidden
#define FD    2048   // ffn
#define NEXP  8
#define NSH   2

using u16 = unsigned short;
typedef __bf16 bf16x8 __attribute__((ext_vector_type(8)));
typedef float  f32x4  __attribute__((ext_vector_type(4)));
typedef u16    u16x2  __attribute__((ext_vector_type(2)));
typedef u16    u16x4  __attribute__((ext_vector_type(4)));

__device__ __forceinline__ u16 f2bf(float f) {
    __hip_bfloat16 h = __float2bfloat16(f);   // RNE
    u16 u; __builtin_memcpy(&u, &h, 2);
    return u;
}
__device__ __forceinline__ float bf2f(u16 u) {
    unsigned v = ((unsigned)u) << 16;
    float f; __builtin_memcpy(&f, &v, 4);
    return f;
}

// async global->LDS, 16B per lane. HW: wave-uniform base + lane*16B.
__device__ __forceinline__ void gl2lds16(const u16* g, u16* l) {
    __builtin_amdgcn_global_load_lds((__attribute__((address_space(1))) void*)(g),
                                     (__attribute__((address_space(3))) void*)(l),
                                     16, 0, 0);
}

// ---------------------------------------------------------------------------
// Core 128x128 tile K-loop (BK=32), 4 waves in 2x2, 4x4 16x16x32 MFMA frags.
// ---------------------------------------------------------------------------
__device__ __forceinline__ void gemm_k_loop(
    const u16* a0, const u16* a1, const u16* b0, const u16* b1,
    u16* As, u16* Bs, int kIters, f32x4 acc[4][4])
{
    const int tid  = threadIdx.x;
    const int wave = tid >> 6, lane = tid & 63;
    const int wm = wave >> 1, wn = wave & 1;
    const int l16 = lane & 15, quad = lane >> 4;
    u16* lA0 = As + (wave * 32 + 0)  * 32 + lane * 8;
    u16* lA1 = As + (wave * 32 + 16) * 32 + lane * 8;
    u16* lB0 = Bs + (wave * 32 + 0)  * 32 + lane * 8;
    u16* lB1 = Bs + (wave * 32 + 16) * 32 + lane * 8;

    for (int kt = 0; kt < kIters; ++kt) {
        gl2lds16(a0, lA0);
        gl2lds16(a1, lA1);
        gl2lds16(b0, lB0);
        gl2lds16(b1, lB1);
        a0 += 32; a1 += 32; b0 += 32; b1 += 32;
        __syncthreads();
        bf16x8 af[4], bfv[4];
#pragma unroll
        for (int i = 0; i < 4; ++i)
            af[i] = *(const bf16x8*)(As + (wm * 64 + i * 16 + l16) * 32 + quad * 8);
#pragma unroll
        for (int j = 0; j < 4; ++j)
            bfv[j] = *(const bf16x8*)(Bs + (wn * 64 + j * 16 + l16) * 32 + quad * 8);
#pragma unroll
        for (int i = 0; i < 4; ++i)
#pragma unroll
            for (int j = 0; j < 4; ++j)
                acc[i][j] = __builtin_amdgcn_mfma_f32_16x16x32_bf16(af[i], bfv[j], acc[i][j], 0, 0, 0);
        __syncthreads();
    }
}

// tanh-form GELU: max abs err ~1e-3 vs exact erf form — negligible after W2.
__device__ __forceinline__ float gelu_fast(float v) {
    float u = v * (0.7978845608028654f + 0.035677408136300125f * v * v);
    return v * __builtin_amdgcn_rcpf(1.0f + __expf(-2.0f * u));
}

// ---------------------------------------------------------------------------
// Coalesced bf16 epilogue: per-wave private LDS region (16 rows x stride 68
// u16 = 2176B; 4 waves fit in the 16KB staging buffer). Writes ds_write_b16
// (conflict-free), reads 4x ds_read_b64, stores 4x 8B per lane => 128B
// contiguous per 4-lane group. No __syncthreads needed (regions disjoint).
// ---------------------------------------------------------------------------
#define EPI_STRIDE 68
template<bool GELU>
__device__ __forceinline__ void epi_store_bf16(
    f32x4 acc[4][4], const float bj[4],
    u16* __restrict__ dst, size_t ld, int rowbase, int colbase, u16* lds)
{
    const int lane = threadIdx.x & 63;
    const int l16 = lane & 15, quad = lane >> 4;
    const int rr = lane >> 2, seg = lane & 3;
#pragma unroll
    for (int i = 0; i < 4; ++i) {
#pragma unroll
        for (int j = 0; j < 4; ++j)
#pragma unroll
            for (int r = 0; r < 4; ++r) {
                float v = acc[i][j][r] + bj[j];
                if (GELU) v = gelu_fast(v);
                lds[(quad * 4 + r) * EPI_STRIDE + j * 16 + l16] = f2bf(v);
            }
        __asm__ volatile("s_waitcnt lgkmcnt(0)" ::: "memory");
        const u16* lp = lds + rr * EPI_STRIDE + seg * 16;
        u16x4 v0 = *(const u16x4*)(lp);
        u16x4 v1 = *(const u16x4*)(lp + 4);
        u16x4 v2 = *(const u16x4*)(lp + 8);
        u16x4 v3 = *(const u16x4*)(lp + 12);
        u16* gp = dst + (size_t)(rowbase + i * 16 + rr) * ld + colbase + seg * 16;
        *(u16x4*)(gp)      = v0;
        *(u16x4*)(gp + 4)  = v1;
        *(u16x4*)(gp + 8)  = v2;
        *(u16x4*)(gp + 12) = v3;
        __asm__ volatile("s_waitcnt lgkmcnt(0)" ::: "memory");  // drain reads before next i overwrites
    }
}

// ---------------------------------------------------------------------------
// Fused convert + router: writes xb (bf16) and fp32 logits top-2 per token.
// ---------------------------------------------------------------------------
__global__ __launch_bounds__(256) void router_convert_kernel(
    const float* __restrict__ x, const float* __restrict__ rw, const float* __restrict__ rb,
    u16* __restrict__ xb, int* __restrict__ cnt, int* __restrict__ lists, int* __restrict__ pos)
{
    const int t = blockIdx.x * 4 + (threadIdx.x >> 6);
    const int lane = threadIdx.x & 63;
    const float* xr = x + (size_t)t * HD;
    u16* xbr = xb + (size_t)t * HD;
    float acc[NEXP];
#pragma unroll
    for (int e = 0; e < NEXP; ++e) acc[e] = 0.f;
#pragma unroll
    for (int it = 0; it < 4; ++it) {
        int h0 = it * 256 + lane * 4;
        float4 v = *(const float4*)(xr + h0);
        ushort4 o = { f2bf(v.x), f2bf(v.y), f2bf(v.z), f2bf(v.w) };
        *(ushort4*)(xbr + h0) = o;
        float xv[4] = { v.x, v.y, v.z, v.w };
#pragma unroll
        for (int q = 0; q < 4; ++q) {
            const float4* wp = (const float4*)(rw + (size_t)(h0 + q) * NEXP);
            float4 w0 = wp[0], w1 = wp[1];
            acc[0] += xv[q] * w0.x; acc[1] += xv[q] * w0.y;
            acc[2] += xv[q] * w0.z; acc[3] += xv[q] * w0.w;
            acc[4] += xv[q] * w1.x; acc[5] += xv[q] * w1.y;
            acc[6] += xv[q] * w1.z; acc[7] += xv[q] * w1.w;
        }
    }
#pragma unroll
    for (int e = 0; e < NEXP; ++e)
        for (int off = 32; off; off >>= 1) acc[e] += __shfl_xor(acc[e], off, 64);
    if (lane == 0) {
#pragma unroll
        for (int e = 0; e < NEXP; ++e) acc[e] += rb[e];
        int b1i = 0;
        for (int e = 1; e < NEXP; ++e) if (acc[e] > acc[b1i]) b1i = e;
        int b2i = (b1i == 0) ? 1 : 0;
        for (int e = 0; e < NEXP; ++e) if (e != b1i && acc[e] > acc[b2i]) b2i = e;
        int p1 = atomicAdd(&cnt[b1i], 1); lists[b1i * T_TOK + p1] = t;
        int p2 = atomicAdd(&cnt[b2i], 1); lists[b2i * T_TOK + p2] = t;
        pos[2 * t]     = (b1i << 13) | p1;
        pos[2 * t + 1] = (b2i << 13) | p2;
    }
}

__global__ void offsets_kernel(const int* __restrict__ cnt, int* __restrict__ pfx) {
    if (threadIdx.x == 0 && blockIdx.x == 0) {
        int s = 0;
        for (int e = 0; e < NEXP; ++e) { pfx[e] = s; s += ((cnt[e] + 127) >> 7) << 7; }
        pfx[NEXP] = s;
    }
}

// ---------------------------------------------------------------------------
// Transposes: fp32 [K,N] -> bf16 [N,K]. 64(dst-contig) x 32 tiles.
// ---------------------------------------------------------------------------
__global__ __launch_bounds__(256) void transpose_w1_kernel(
    const float* __restrict__ sw1, const float* __restrict__ ew1, u16* __restrict__ wt)
{
    __shared__ u16 tile[32][65];
    const int z = blockIdx.z;
    const float* src = (z < NSH) ? (sw1 + (size_t)z * HD * FD)
                                 : (ew1 + (size_t)(z - NSH) * HD * FD);
    u16* dst = wt + (size_t)z * FD * HD;           // [f][h], ld = HD
    const int tx = threadIdx.x, ty = threadIdx.y;  // (32, 8)
    const int c0 = blockIdx.x * 32;                // over FD (dst rows)
    const int r0 = blockIdx.y * 64;                // over HD (dst contig)
#pragma unroll
    for (int k = 0; k < 8; ++k)
        tile[tx][ty + 8 * k] = f2bf(src[(size_t)(r0 + ty + 8 * k) * FD + c0 + tx]);
    __syncthreads();
#pragma unroll
    for (int k = 0; k < 4; ++k) {
        int c = ty + 8 * k;
        u16x2 v = { tile[c][2 * tx], tile[c][2 * tx + 1] };
        *(u16x2*)(dst + (size_t)(c0 + c) * HD + r0 + 2 * tx) = v;
    }
}

// shared_w2[s][f][h] -> w2tS[h][s*FD+f] (ld=2FD);  exp_w2[e][f][h] -> [e][h][f]
__global__ __launch_bounds__(256) void transpose_w2_kernel(
    const float* __restrict__ sw2, const float* __restrict__ ew2, u16* __restrict__ wt)
{
    __shared__ u16 tile[32][65];
    const int z = blockIdx.z;
    const float* src; u16* dst; size_t ldd;
    if (z < NSH) { src = sw2 + (size_t)z * FD * HD; dst = wt + (size_t)z * FD; ldd = 2 * FD; }
    else { src = ew2 + (size_t)(z - NSH) * FD * HD;
           dst = wt + (size_t)NSH * FD * HD + (size_t)(z - NSH) * HD * FD; ldd = FD; }
    const int tx = threadIdx.x, ty = threadIdx.y;  // (32, 8)
    const int c0 = blockIdx.x * 32;                // over HD (dst rows h)
    const int r0 = blockIdx.y * 64;                // over FD (dst contig f)
#pragma unroll
    for (int k = 0; k < 8; ++k)
        tile[tx][ty + 8 * k] = f2bf(src[(size_t)(r0 + ty + 8 * k) * HD + c0 + tx]);
    __syncthreads();
#pragma unroll
    for (int k = 0; k < 4; ++k) {
        int c = ty + 8 * k;
        u16x2 v = { tile[c][2 * tx], tile[c][2 * tx + 1] };
        *(u16x2*)(dst + (size_t)(c0 + c) * ldd + r0 + 2 * tx) = v;
    }
}

// ---------------------------------------------------------------------------
// GEMM1 merged: z<NSH -> shared expert s=z (hidS[t][s*FD+f]);
//               z>=NSH -> routed expert e=z-NSH (hidE[pfx[e]+slot][f]).
// ---------------------------------------------------------------------------
__global__ __launch_bounds__(256, 4) void gemm1_all_kernel(
    const u16* __restrict__ xb, const u16* __restrict__ w1t,
    const float* __restrict__ sb1, const float* __restrict__ eb1,
    const int* __restrict__ cnt, const int* __restrict__ pfx,
    const int* __restrict__ lists,
    u16* __restrict__ hidS, u16* __restrict__ hidE)
{
    const int z = blockIdx.z, nt = blockIdx.x, mt = blockIdx.y;
    const bool routed = (z >= NSH);
    const int e = z - NSH;
    if (routed && mt * 128 >= cnt[e]) return;   // block-uniform early exit
    __shared__ __align__(16) u16 S[2 * 128 * 32];
    u16* As = S;
    u16* Bs = S + 128 * 32;
    const int tid = threadIdx.x, wave = tid >> 6, lane = tid & 63;
    const int r0 = wave * 32 + (lane >> 2), ch = (lane & 3) * 8;
    const u16 *a0, *a1;
    if (routed) {
        int tok0 = lists[e * T_TOK + mt * 128 + r0];
        int tok1 = lists[e * T_TOK + mt * 128 + r0 + 16];
        a0 = xb + (size_t)tok0 * HD + ch;
        a1 = xb + (size_t)tok1 * HD + ch;
    } else {
        a0 = xb + (size_t)(mt * 128 + r0) * HD + ch;
        a1 = a0 + (size_t)16 * HD;
    }
    const u16* b0 = w1t + (size_t)z * FD * HD + (size_t)(nt * 128 + r0) * HD + ch;
    const u16* b1 = b0 + (size_t)16 * HD;
    f32x4 acc[4][4] = {};
    gemm_k_loop(a0, a1, b0, b1, As, Bs, HD / 32, acc);

    const int wm = wave >> 1, wn = wave & 1, l16 = lane & 15;
    const float* bias = routed ? (eb1 + e * FD) : (sb1 + z * FD);
    float bj[4];
#pragma unroll
    for (int j = 0; j < 4; ++j) bj[j] = bias[nt * 128 + wn * 64 + j * 16 + l16];
    u16* dst   = routed ? hidE : hidS;
    const size_t ld = routed ? FD : 2 * FD;
    const int rowbase = (routed ? (pfx[e] + mt * 128) : (mt * 128)) + wm * 64;
    const int colbase = (routed ? 0 : z * FD) + nt * 128 + wn * 64;
    epi_store_bf16<true>(acc, bj, dst, ld, rowbase, colbase, S + wave * 16 * EPI_STRIDE);
}

// ---------------------------------------------------------------------------
// GEMM2 merged, NO atomics: z==0 -> shared (K=4096 over both experts, plain
// fp32 stores directly to out w/ both biases); z>=1 -> routed expert e=z-1
// (K=2048, coalesced bf16 stores to routedOut[slot] w/ bias).
// ---------------------------------------------------------------------------
__global__ __launch_bounds__(256, 4) void gemm2_all_kernel(
    const u16* __restrict__ hidS, const u16* __restrict__ hidE,
    const u16* __restrict__ w2t,
    const float* __restrict__ sb2, const float* __restrict__ eb2,
    const int* __restrict__ cnt, const int* __restrict__ pfx,
    float* __restrict__ out, u16* __restrict__ routedOut)
{
    const int z = blockIdx.z, nt = blockIdx.x, mt = blockIdx.y;
    const int e = z - 1;
    if (z >= 1 && mt * 128 >= cnt[e]) return;
    __shared__ __align__(16) u16 S[2 * 128 * 32];
    u16* As = S;
    u16* Bs = S + 128 * 32;
    const int tid = threadIdx.x, wave = tid >> 6, lane = tid & 63;
    const int r0 = wave * 32 + (lane >> 2), ch = (lane & 3) * 8;
    const int wm = wave >> 1, wn = wave & 1, l16 = lane & 15, quad = lane >> 4;
    f32x4 acc[4][4] = {};

    if (z == 0) {
        const u16* a0 = hidS + (size_t)(mt * 128 + r0) * (2 * FD) + ch;
        const u16* a1 = a0 + (size_t)16 * (2 * FD);
        const u16* b0 = w2t + (size_t)(nt * 128 + r0) * (2 * FD) + ch;
        const u16* b1 = b0 + (size_t)16 * (2 * FD);
        gemm_k_loop(a0, a1, b0, b1, As, Bs, (2 * FD) / 32, acc);
#pragma unroll
        for (int j = 0; j < 4; ++j) {
            int h = nt * 128 + wn * 64 + j * 16 + l16;
            float bv = sb2[h] + sb2[HD + h];
#pragma unroll
            for (int i = 0; i < 4; ++i) {
                int row = mt * 128 + wm * 64 + i * 16 + quad * 4;
#pragma unroll
                for (int r = 0; r < 4; ++r)
                    out[(size_t)(row + r) * HD + h] = acc[i][j][r] + bv;
            }
        }
    } else {
        const int base = pfx[e];
        const u16* a0 = hidE + (size_t)(base + mt * 128 + r0) * FD + ch;
        const u16* a1 = a0 + (size_t)16 * FD;
        const u16* b0 = w2t + (size_t)NSH * FD * HD + (size_t)e * HD * FD
                            + (size_t)(nt * 128 + r0) * FD + ch;
        const u16* b1 = b0 + (size_t)16 * FD;
        gemm_k_loop(a0, a1, b0, b1, As, Bs, FD / 32, acc);
        float bj[4];
#pragma unroll
        for (int j = 0; j < 4; ++j) bj[j] = eb2[e * HD + nt * 128 + wn * 64 + j * 16 + l16];
        epi_store_bf16<false>(acc, bj, routedOut, HD,
                              base + mt * 128 + wm * 64, nt * 128 + wn * 64,
                              S + wave * 16 * EPI_STRIDE);
    }
}

// Fallback (small-ws): routed scatters via atomicAdd onto out (which the
// shared pass already fully wrote). K unsplit, bias added once per (t,h,e).
__global__ __launch_bounds__(256, 4) void gemm2_routed_atomic_kernel(
    const u16* __restrict__ hidE, const u16* __restrict__ w2t,
    const float* __restrict__ eb2, const int* __restrict__ cnt,
    const int* __restrict__ pfx, const int* __restrict__ lists,
    float* __restrict__ out)
{
    const int e = blockIdx.z, nt = blockIdx.x, mt = blockIdx.y;
    const int n_e = cnt[e];
    if (mt * 128 >= n_e) return;
    __shared__ __align__(16) u16 S[2 * 128 * 32];
    u16* As = S;
    u16* Bs = S + 128 * 32;
    const int tid = threadIdx.x, wave = tid >> 6, lane = tid & 63;
    const int r0 = wave * 32 + (lane >> 2), ch = (lane & 3) * 8;
    const int base = pfx[e];
    const u16* a0 = hidE + (size_t)(base + mt * 128 + r0) * FD + ch;
    const u16* a1 = a0 + (size_t)16 * FD;
    const u16* b0 = w2t + (size_t)NSH * FD * HD + (size_t)e * HD * FD
                        + (size_t)(nt * 128 + r0) * FD + ch;
    const u16* b1 = b0 + (size_t)16 * FD;
    f32x4 acc[4][4] = {};
    gemm_k_loop(a0, a1, b0, b1, As, Bs, FD / 32, acc);
    const int wm = wave >> 1, wn = wave & 1, l16 = lane & 15, quad = lane >> 4;
#pragma unroll
    for (int j = 0; j < 4; ++j) {
        int h = nt * 128 + wn * 64 + j * 16 + l16;
        float bv = eb2[e * HD + h];
#pragma unroll
        for (int i = 0; i < 4; ++i) {
            int local = mt * 128 + wm * 64 + i * 16 + quad * 4;
#pragma unroll
            for (int r = 0; r < 4; ++r)
                if (local + r < n_e) {
                    int t = lists[e * T_TOK + local + r];
                    atomicAdd(&out[(size_t)t * HD + h], acc[i][j][r] + bv);
                }
        }
    }
}

// out[t][:] += routedOut[row1][:] + routedOut[row2][:]
__global__ __launch_bounds__(256) void finalize_kernel(
    const u16* __restrict__ routedOut, const int* __restrict__ pos,
    const int* __restrict__ pfx, float* __restrict__ out)
{
    const int t = blockIdx.x;
    int enc0 = pos[2 * t], enc1 = pos[2 * t + 1];
    int row0 = pfx[enc0 >> 13] + (enc0 & 8191);
    int row1 = pfx[enc1 >> 13] + (enc1 & 8191);
    int h = threadIdx.x * 4;
    ushort4 a = *(const ushort4*)(routedOut + (size_t)row0 * HD + h);
    ushort4 b = *(const ushort4*)(routedOut + (size_t)row1 * HD + h);
    float* po = out + (size_t)t * HD + h;
    float4 o = *(const float4*)po;
    o.x += bf2f(a.x) + bf2f(b.x);
    o.y += bf2f(a.y) + bf2f(b.y);
    o.z += bf2f(a.z) + bf2f(b.z);
    o.w += bf2f(a.w) + bf2f(b.w);
    *(float4*)po = o;
}

// ---------------------------------------------------------------------------
// Workspace layout (bytes):
//   wt        @ 0           : 41,943,040  (w1^T, later reused for w2^T)
//   hidS      @ 41,943,040  : 33,554,432  (bf16 [4096][2*FD])
//   hidE      @ 75,497,472  : 37,748,736  (bf16 [9216][FD])
//   xb        @ 113,246,208 :  8,388,608  (dead after gemm1)
//   routedOut @ 113,246,208 : 18,874,368  (overlays xb; lifetimes disjoint)
// primary: smalls @ 132,120,576 (cnt 64 | pfx 64 | lists 131072 | pos 32768)
//          -> total 132,284,544
// fallback: smalls @ 121,634,816 -> total 121,798,784 (proven-safe size)
// ---------------------------------------------------------------------------
extern "C" void kernel_launch(void* const* d_in, const int* in_sizes, int n_in,
                              void* d_out, int out_size, void* d_ws, size_t ws_size,
                              hipStream_t stream)
{
    (void)in_sizes; (void)n_in; (void)out_size;
    const float* x   = (const float*)d_in[0];
    const float* sw1 = (const float*)d_in[1];
    const float* sb1 = (const float*)d_in[2];
    const float* sw2 = (const float*)d_in[3];
    const float* sb2 = (const float*)d_in[4];
    const float* ew1 = (const float*)d_in[5];
    const float* eb1 = (const float*)d_in[6];
    const float* ew2 = (const float*)d_in[7];
    const float* eb2 = (const float*)d_in[8];
    const float* rw  = (const float*)d_in[9];
    const float* rb  = (const float*)d_in[10];
    float* out = (float*)d_out;

    const bool plain = (ws_size >= (size_t)132284544);
    char* ws   = (char*)d_ws;
    u16*  wt   = (u16*)ws;
    u16*  hidS = (u16*)(ws + 41943040);
    u16*  hidE = (u16*)(ws + 75497472);
    u16*  xb   = (u16*)(ws + 113246208);
    u16*  rOut = (u16*)(ws + 113246208);   // overlays xb
    size_t smallOfs = plain ? (size_t)132120576 : (size_t)121634816;
    int*  cnt   = (int*)(ws + smallOfs);
    int*  pfx   = (int*)(ws + smallOfs + 64);
    int*  lists = (int*)(ws + smallOfs + 128);
    int*  pos   = (int*)(ws + smallOfs + 128 + NEXP * T_TOK * 4);

    hipMemsetAsync(cnt, 0, 128 + (size_t)NEXP * T_TOK * 4, stream);  // cnt+pfx+lists

    router_convert_kernel<<<dim3(T_TOK / 4), dim3(256), 0, stream>>>(x, rw, rb, xb, cnt, lists, pos);
    offsets_kernel<<<dim3(1), dim3(64), 0, stream>>>(cnt, pfx);
    transpose_w1_kernel<<<dim3(FD / 32, HD / 64, NSH + NEXP), dim3(32, 8), 0, stream>>>(sw1, ew1, wt);

    gemm1_all_kernel<<<dim3(FD / 128, T_TOK / 128, NSH + NEXP), dim3(256), 0, stream>>>(
        xb, wt, sb1, eb1, cnt, pfx, lists, hidS, hidE);

    transpose_w2_kernel<<<dim3(HD / 32, FD / 64, NSH + NEXP), dim3(32, 8), 0, stream>>>(sw2, ew2, wt);

    if (plain) {
        gemm2_all_kernel<<<dim3(HD / 128, T_TOK / 128, 1 + NEXP), dim3(256), 0, stream>>>(
            hidS, hidE, wt, sb2, eb2, cnt, pfx, out, rOut);
        finalize_kernel<<<dim3(T_TOK), dim3(256), 0, stream>>>(rOut, pos, pfx, out);
    } else {
        gemm2_all_kernel<<<dim3(HD / 128, T_TOK / 128, 1), dim3(256), 0, stream>>>(
            hidS, hidE, wt, sb2, eb2, cnt, pfx, out, rOut);  // z=0 shared only
        gemm2_routed_atomic_kernel<<<dim3(HD / 128, T_TOK / 128, NEXP), dim3(256), 0, stream>>>(
            hidE, wt, eb2, cnt, pfx, lists, out);
    }
}